// Round 1
// baseline (2867.064 us; speedup 1.0000x reference)
//
#include <hip/hip_runtime.h>

// ---------------------------------------------------------------------------
// TAGConv (K=2) x2 + mean pool.
// Math reorder: concat([h, Ah, A^2 h]) @ [W0;W1;W2] + b
//             = h@W0 + A(h@W1 + A(h@W2)) + b      (A = norm-scaled adjacency)
// Layer 1: GEMM-first with two N*128 buffers.
// Layer 2: GEMM-first -> sparse hops run at d=40 instead of d=128.
// CSR built on device each call (int atomics only), SpMM is wave-per-node.
// ---------------------------------------------------------------------------

__global__ void zero_int_k(int* __restrict__ p, int n) {
    int i = blockIdx.x * 256 + threadIdx.x;
    if (i < n) p[i] = 0;
}

__global__ void edge_deg_k(const int* __restrict__ dst, int* __restrict__ deg, int E) {
    int e = blockIdx.x * 256 + threadIdx.x;
    if (e < E) atomicAdd(&deg[dst[e]], 1);
}

__global__ void norm_k(const int* __restrict__ deg, float* __restrict__ norm, int n) {
    int i = blockIdx.x * 256 + threadIdx.x;
    if (i < n) {
        int d = deg[i];
        norm[i] = (d > 0) ? rsqrtf((float)d) : 0.f;
    }
}

// exclusive scan of deg -> rowptr (3 kernels, 1024 elems/block)
__global__ void scan1_k(const int* __restrict__ deg, int* __restrict__ rowptr,
                        int* __restrict__ bsum, int n) {
    __shared__ int lds[256];
    int t = threadIdx.x;
    int base = blockIdx.x * 1024 + t * 4;
    int v[4];
    int s = 0;
#pragma unroll
    for (int i = 0; i < 4; ++i) {
        v[i] = s;
        int idx = base + i;
        s += (idx < n) ? deg[idx] : 0;
    }
    int x = s;
    lds[t] = x;
    __syncthreads();
    for (int off = 1; off < 256; off <<= 1) {
        int y = (t >= off) ? lds[t - off] : 0;
        __syncthreads();
        x += y;
        lds[t] = x;
        __syncthreads();
    }
    int toff = x - s;  // exclusive prefix of this thread's chunk
    if (t == 255) bsum[blockIdx.x] = x;
#pragma unroll
    for (int i = 0; i < 4; ++i) {
        int idx = base + i;
        if (idx < n) rowptr[idx] = toff + v[i];
    }
}

__global__ void scan2_k(int* __restrict__ bsum, int nb) {
    if (blockIdx.x == 0 && threadIdx.x == 0) {
        int run = 0;
        for (int i = 0; i < nb; ++i) { int t = bsum[i]; bsum[i] = run; run += t; }
    }
}

__global__ void scan3_k(int* __restrict__ rowptr, int* __restrict__ cursor,
                        const int* __restrict__ bsum, int n, int E) {
    int t = threadIdx.x;
    int base = blockIdx.x * 1024 + t * 4;
    int boff = bsum[blockIdx.x];
#pragma unroll
    for (int i = 0; i < 4; ++i) {
        int idx = base + i;
        if (idx < n) {
            int v = rowptr[idx] + boff;
            rowptr[idx] = v;
            cursor[idx] = v;
        }
    }
    if (blockIdx.x == 0 && t == 0) rowptr[n] = E;
}

__global__ void scatter_k(const int* __restrict__ src, const int* __restrict__ dst,
                          int* __restrict__ cursor, int* __restrict__ esrc, int E) {
    int e = blockIdx.x * 256 + threadIdx.x;
    if (e < E) {
        int p = atomicAdd(&cursor[dst[e]], 1);
        esrc[p] = src[e];
    }
}

// ---------------------------------------------------------------------------
// C[n,M] = A[n,128] @ B[128,M]  (+ addp) (+ bias) (relu?)
// block = 256 threads, 16 rows/block (4 waves x 4 rows), B staged in LDS.
// ---------------------------------------------------------------------------
template <int M, bool HAS_ADD, bool HAS_BIAS, bool RELU>
__global__ __launch_bounds__(256) void gemm_k(
    const float* __restrict__ A, const float* __restrict__ B, float* __restrict__ C,
    const float* __restrict__ addp, const float* __restrict__ bias, int n) {
    __shared__ float Bs[128 * M];
    for (int i = threadIdx.x; i < 128 * M / 4; i += 256)
        ((float4*)Bs)[i] = ((const float4*)B)[i];
    __syncthreads();

    int lane = threadIdx.x & 63;
    int wave = threadIdx.x >> 6;
    int r0 = blockIdx.x * 16 + wave * 4;

    int rA[4];
#pragma unroll
    for (int rr = 0; rr < 4; ++rr) rA[rr] = min(r0 + rr, n - 1);

    if (M == 128) {
        float acc0[4] = {0, 0, 0, 0}, acc1[4] = {0, 0, 0, 0};
        for (int k = 0; k < 128; k += 4) {
            float4 av[4];
#pragma unroll
            for (int rr = 0; rr < 4; ++rr)
                av[rr] = *(const float4*)(A + (size_t)rA[rr] * 128 + k);
#pragma unroll
            for (int kk = 0; kk < 4; ++kk) {
                float b0 = Bs[(k + kk) * 128 + lane];
                float b1 = Bs[(k + kk) * 128 + 64 + lane];
#pragma unroll
                for (int rr = 0; rr < 4; ++rr) {
                    float a = ((const float*)&av[rr])[kk];
                    acc0[rr] = fmaf(a, b0, acc0[rr]);
                    acc1[rr] = fmaf(a, b1, acc1[rr]);
                }
            }
        }
#pragma unroll
        for (int rr = 0; rr < 4; ++rr) {
            int r = r0 + rr;
            if (r >= n) break;
            float v0 = acc0[rr], v1 = acc1[rr];
            if (HAS_ADD) {
                v0 += addp[(size_t)r * 128 + lane];
                v1 += addp[(size_t)r * 128 + 64 + lane];
            }
            if (HAS_BIAS) { v0 += bias[lane]; v1 += bias[64 + lane]; }
            if (RELU) { v0 = fmaxf(v0, 0.f); v1 = fmaxf(v1, 0.f); }
            C[(size_t)r * 128 + lane] = v0;
            C[(size_t)r * 128 + 64 + lane] = v1;
        }
    } else {  // M == 40
        float acc[4] = {0, 0, 0, 0};
        int cl = (lane < 40) ? lane : 39;
        for (int k = 0; k < 128; k += 4) {
            float4 av[4];
#pragma unroll
            for (int rr = 0; rr < 4; ++rr)
                av[rr] = *(const float4*)(A + (size_t)rA[rr] * 128 + k);
#pragma unroll
            for (int kk = 0; kk < 4; ++kk) {
                float b = Bs[(k + kk) * 40 + cl];
#pragma unroll
                for (int rr = 0; rr < 4; ++rr) {
                    float a = ((const float*)&av[rr])[kk];
                    acc[rr] = fmaf(a, b, acc[rr]);
                }
            }
        }
        if (lane < 40) {
#pragma unroll
            for (int rr = 0; rr < 4; ++rr) {
                int r = r0 + rr;
                if (r >= n) break;
                float v = acc[rr];
                if (HAS_ADD) v += addp[(size_t)r * 40 + lane];
                if (HAS_BIAS) v += bias[lane];
                if (RELU) v = fmaxf(v, 0.f);
                C[(size_t)r * 40 + lane] = v;
            }
        }
    }
}

// out[n,:] = norm[n] * sum_{e in in(n)} norm[src] * in[src,:]   (d = 128)
__global__ __launch_bounds__(256) void spmm128_k(
    const float* __restrict__ in, float* __restrict__ out, const float* __restrict__ norm,
    const int* __restrict__ rowptr, const int* __restrict__ esrc, int n) {
    int gw = (blockIdx.x * 256 + threadIdx.x) >> 6;
    int lane = threadIdx.x & 63;
    if (gw >= n) return;
    int beg = rowptr[gw], end = rowptr[gw + 1];
    float a0 = 0.f, a1 = 0.f;
    for (int e = beg; e < end; ++e) {
        int s = esrc[e];
        float ns = norm[s];
        float2 v = *(const float2*)(in + (size_t)s * 128 + lane * 2);
        a0 = fmaf(ns, v.x, a0);
        a1 = fmaf(ns, v.y, a1);
    }
    float nn = norm[gw];
    float2 o;
    o.x = a0 * nn;
    o.y = a1 * nn;
    *(float2*)(out + (size_t)gw * 128 + lane * 2) = o;
}

// out = addp + Ahat(in), d = 40
__global__ __launch_bounds__(256) void spmm40_k(
    const float* __restrict__ in, const float* __restrict__ addp, float* __restrict__ out,
    const float* __restrict__ norm, const int* __restrict__ rowptr,
    const int* __restrict__ esrc, int n) {
    int gw = (blockIdx.x * 256 + threadIdx.x) >> 6;
    int lane = threadIdx.x & 63;
    if (gw >= n || lane >= 40) return;
    int beg = rowptr[gw], end = rowptr[gw + 1];
    float a = 0.f;
    for (int e = beg; e < end; ++e) {
        int s = esrc[e];
        a = fmaf(norm[s], in[(size_t)s * 40 + lane], a);
    }
    out[(size_t)gw * 40 + lane] = addp[(size_t)gw * 40 + lane] + norm[gw] * a;
}

// r = relu(z0 + Ahat(u) + b2); partial[block] = sum_nodes r  (mean pool stage 1)
__global__ __launch_bounds__(256) void spmm40_final_k(
    const float* __restrict__ u, const float* __restrict__ z0, const float* __restrict__ bias,
    float* __restrict__ partial, const float* __restrict__ norm,
    const int* __restrict__ rowptr, const int* __restrict__ esrc, int n, int nwaves) {
    __shared__ float lds[4][40];
    int wave = threadIdx.x >> 6;
    int lane = threadIdx.x & 63;
    int gw0 = blockIdx.x * 4 + wave;
    float accm = 0.f;
    float bb = (lane < 40) ? bias[lane] : 0.f;
    for (int node = gw0; node < n; node += nwaves) {
        if (lane < 40) {
            int beg = rowptr[node], end = rowptr[node + 1];
            float a = 0.f;
            for (int e = beg; e < end; ++e) {
                int s = esrc[e];
                a = fmaf(norm[s], u[(size_t)s * 40 + lane], a);
            }
            float r = z0[(size_t)node * 40 + lane] + norm[node] * a + bb;
            accm += fmaxf(r, 0.f);
        }
    }
    if (lane < 40) lds[wave][lane] = accm;
    __syncthreads();
    if (threadIdx.x < 40) {
        partial[blockIdx.x * 40 + threadIdx.x] =
            lds[0][threadIdx.x] + lds[1][threadIdx.x] + lds[2][threadIdx.x] + lds[3][threadIdx.x];
    }
}

__global__ void reduce_mean_k(const float* __restrict__ partial, float* __restrict__ out,
                              int nb, float invN) {
    int c = threadIdx.x;
    if (c < 40) {
        float s = 0.f;
        for (int b = 0; b < nb; ++b) s += partial[b * 40 + c];
        out[c] = s * invN;
    }
}

extern "C" void kernel_launch(void* const* d_in, const int* in_sizes, int n_in,
                              void* d_out, int out_size, void* d_ws, size_t ws_size,
                              hipStream_t stream) {
    const float* X  = (const float*)d_in[0];
    const int*   src = (const int*)d_in[1];
    const int*   dst = (const int*)d_in[2];
    const float* W1 = (const float*)d_in[3];
    const float* b1 = (const float*)d_in[4];
    const float* W2 = (const float*)d_in[5];
    const float* b2 = (const float*)d_in[6];
    float* out = (float*)d_out;

    const int IN = 128;
    const int N = in_sizes[0] / IN;
    const int E = in_sizes[1];

    char* w = (char*)d_ws;
    size_t off = 0;
    auto alloc = [&](size_t bytes) -> char* {
        char* p = w + off;
        off = (off + bytes + 15) & ~(size_t)15;
        return p;
    };
    float* norm   = (float*)alloc((size_t)N * 4);
    int*   deg    = (int*)alloc((size_t)N * 4);
    int*   rowptr = (int*)alloc((size_t)(N + 1) * 4);
    int*   cursor = (int*)alloc((size_t)N * 4);
    int*   bsum   = (int*)alloc(1024 * 4);
    int*   esrc   = (int*)alloc((size_t)E * 4);
    float* bufA   = (float*)alloc((size_t)N * 128 * 4);
    float* bufB   = (float*)alloc((size_t)N * 128 * 4);
    float* partial= (float*)alloc(256 * 40 * 4);

    int nb_scan = (N + 1023) / 1024;

    // ---- graph preprocessing: degree, norm, CSR by dst ----
    zero_int_k<<<(N + 255) / 256, 256, 0, stream>>>(deg, N);
    edge_deg_k<<<(E + 255) / 256, 256, 0, stream>>>(dst, deg, E);
    norm_k<<<(N + 255) / 256, 256, 0, stream>>>(deg, norm, N);
    scan1_k<<<nb_scan, 256, 0, stream>>>(deg, rowptr, bsum, N);
    scan2_k<<<1, 64, 0, stream>>>(bsum, nb_scan);
    scan3_k<<<nb_scan, 256, 0, stream>>>(rowptr, cursor, bsum, N, E);
    scatter_k<<<(E + 255) / 256, 256, 0, stream>>>(src, dst, cursor, esrc, E);

    int gemm_grid = (N + 15) / 16;
    int spmm_grid = (N + 3) / 4;

    // ---- layer 1: h1 = relu(X@W1_0 + A(X@W1_1 + A(X@W1_2)) + b1) ----
    gemm_k<128, false, false, false><<<gemm_grid, 256, 0, stream>>>(
        X, W1 + 2 * 128 * 128, bufA, nullptr, nullptr, N);
    spmm128_k<<<spmm_grid, 256, 0, stream>>>(bufA, bufB, norm, rowptr, esrc, N);
    gemm_k<128, true, false, false><<<gemm_grid, 256, 0, stream>>>(
        X, W1 + 1 * 128 * 128, bufB, bufB, nullptr, N);
    spmm128_k<<<spmm_grid, 256, 0, stream>>>(bufB, bufA, norm, rowptr, esrc, N);
    gemm_k<128, true, true, true><<<gemm_grid, 256, 0, stream>>>(
        X, W1, bufB, bufA, b1, N);   // bufB = h1

    // ---- layer 2: out = mean(relu(Z0 + A(Z1 + A(Z2)) + b2)) ----
    float* Z0 = bufA;
    float* Z1 = bufA + (size_t)N * 40;
    float* Z2 = bufA + (size_t)2 * N * 40;
    gemm_k<40, false, false, false><<<gemm_grid, 256, 0, stream>>>(
        bufB, W2 + 0 * 128 * 40, Z0, nullptr, nullptr, N);
    gemm_k<40, false, false, false><<<gemm_grid, 256, 0, stream>>>(
        bufB, W2 + 1 * 128 * 40, Z1, nullptr, nullptr, N);
    gemm_k<40, false, false, false><<<gemm_grid, 256, 0, stream>>>(
        bufB, W2 + 2 * 128 * 40, Z2, nullptr, nullptr, N);
    spmm40_k<<<spmm_grid, 256, 0, stream>>>(Z2, Z1, bufB, norm, rowptr, esrc, N);
    spmm40_final_k<<<256, 256, 0, stream>>>(bufB, Z0, b2, partial, norm, rowptr, esrc, N, 1024);
    reduce_mean_k<<<1, 64, 0, stream>>>(partial, out, 256, 1.f / (float)N);
}

// Round 2
// 2191.208 us; speedup vs baseline: 1.3084x; 1.3084x over previous
//
#include <hip/hip_runtime.h>

// ---------------------------------------------------------------------------
// TAGConv (K=2) x2 + mean pool.
//   concat([h, Ah, A^2 h]) @ [W0;W1;W2] + b = h@W0 + A(h@W1 + A(h@W2)) + b
// D^{-1/2} folded into GEMM epilogues -> SpMMs are pure gather-sums.
// Layer 2 GEMMs merged into one M=120 kernel (sparse hops at d=40).
// ---------------------------------------------------------------------------

__global__ void zero_int_k(int* __restrict__ p, int n) {
    int i = blockIdx.x * 256 + threadIdx.x;
    if (i < n) p[i] = 0;
}

__global__ void edge_deg_k(const int* __restrict__ dst, int* __restrict__ deg, int E) {
    int e = blockIdx.x * 256 + threadIdx.x;
    if (e < E) atomicAdd(&deg[dst[e]], 1);
}

__global__ void norm_k(const int* __restrict__ deg, float* __restrict__ norm, int n) {
    int i = blockIdx.x * 256 + threadIdx.x;
    if (i < n) {
        int d = deg[i];
        norm[i] = (d > 0) ? rsqrtf((float)d) : 0.f;
    }
}

// exclusive scan of deg -> rowptr (3 kernels, 1024 elems/block)
__global__ void scan1_k(const int* __restrict__ deg, int* __restrict__ rowptr,
                        int* __restrict__ bsum, int n) {
    __shared__ int lds[256];
    int t = threadIdx.x;
    int base = blockIdx.x * 1024 + t * 4;
    int v[4];
    int s = 0;
#pragma unroll
    for (int i = 0; i < 4; ++i) {
        v[i] = s;
        int idx = base + i;
        s += (idx < n) ? deg[idx] : 0;
    }
    int x = s;
    lds[t] = x;
    __syncthreads();
    for (int off = 1; off < 256; off <<= 1) {
        int y = (t >= off) ? lds[t - off] : 0;
        __syncthreads();
        x += y;
        lds[t] = x;
        __syncthreads();
    }
    int toff = x - s;
    if (t == 255) bsum[blockIdx.x] = x;
#pragma unroll
    for (int i = 0; i < 4; ++i) {
        int idx = base + i;
        if (idx < n) rowptr[idx] = toff + v[i];
    }
}

__global__ void scan2_k(int* __restrict__ bsum, int nb) {
    if (blockIdx.x == 0 && threadIdx.x == 0) {
        int run = 0;
        for (int i = 0; i < nb; ++i) { int t = bsum[i]; bsum[i] = run; run += t; }
    }
}

__global__ void scan3_k(int* __restrict__ rowptr, int* __restrict__ cursor,
                        const int* __restrict__ bsum, int n, int E) {
    int t = threadIdx.x;
    int base = blockIdx.x * 1024 + t * 4;
    int boff = bsum[blockIdx.x];
#pragma unroll
    for (int i = 0; i < 4; ++i) {
        int idx = base + i;
        if (idx < n) {
            int v = rowptr[idx] + boff;
            rowptr[idx] = v;
            cursor[idx] = v;
        }
    }
    if (blockIdx.x == 0 && t == 0) rowptr[n] = E;
}

__global__ void scatter_k(const int* __restrict__ src, const int* __restrict__ dst,
                          int* __restrict__ cursor, int* __restrict__ esrc, int E) {
    int e = blockIdx.x * 256 + threadIdx.x;
    if (e < E) {
        int p = atomicAdd(&cursor[dst[e]], 1);
        esrc[p] = src[e];
    }
}

// ---------------------------------------------------------------------------
// C[n,128] = A[n,128] @ B[128,128] with norm-folding epilogues.
// MODE 1: C = norm*dot
// MODE 2: C = norm*(dot + norm*addp)   (in-place addp==C is safe)
// MODE 3: C = relu(dot + norm*addp + bias)
// block = 256 (4 waves x 4 rows = 16 rows), each thread cols {2*lane, 2*lane+1}.
// ---------------------------------------------------------------------------
template <int MODE>
__global__ __launch_bounds__(256) void gemm128_k(
    const float* __restrict__ A, const float* __restrict__ B, float* __restrict__ C,
    const float* __restrict__ addp, const float* __restrict__ bias,
    const float* __restrict__ norm, int n) {
    __shared__ float Bs[128 * 128];
    for (int i = threadIdx.x; i < 128 * 128 / 4; i += 256)
        ((float4*)Bs)[i] = ((const float4*)B)[i];
    __syncthreads();

    int lane = threadIdx.x & 63;
    int wave = threadIdx.x >> 6;
    int r0 = blockIdx.x * 16 + wave * 4;
    int c0 = lane * 2;

    int rA[4];
#pragma unroll
    for (int rr = 0; rr < 4; ++rr) rA[rr] = min(r0 + rr, n - 1);

    float acc0[4] = {0, 0, 0, 0}, acc1[4] = {0, 0, 0, 0};
    for (int k = 0; k < 128; k += 4) {
        float4 av[4];
#pragma unroll
        for (int rr = 0; rr < 4; ++rr)
            av[rr] = *(const float4*)(A + (size_t)rA[rr] * 128 + k);
#pragma unroll
        for (int kk = 0; kk < 4; ++kk) {
            float2 b = *(const float2*)&Bs[(k + kk) * 128 + c0];
#pragma unroll
            for (int rr = 0; rr < 4; ++rr) {
                float a = ((const float*)&av[rr])[kk];
                acc0[rr] = fmaf(a, b.x, acc0[rr]);
                acc1[rr] = fmaf(a, b.y, acc1[rr]);
            }
        }
    }
#pragma unroll
    for (int rr = 0; rr < 4; ++rr) {
        int r = r0 + rr;
        if (r >= n) break;
        float nr = norm[r];
        float v0 = acc0[rr], v1 = acc1[rr];
        if (MODE == 1) { v0 *= nr; v1 *= nr; }
        if (MODE == 2) {
            float2 ap = *(const float2*)(addp + (size_t)r * 128 + c0);
            v0 = nr * (v0 + nr * ap.x);
            v1 = nr * (v1 + nr * ap.y);
        }
        if (MODE == 3) {
            float2 ap = *(const float2*)(addp + (size_t)r * 128 + c0);
            float2 bb = *(const float2*)(bias + c0);
            v0 = fmaxf(v0 + nr * ap.x + bb.x, 0.f);
            v1 = fmaxf(v1 + nr * ap.y + bb.y, 0.f);
        }
        float2 o; o.x = v0; o.y = v1;
        *(float2*)(C + (size_t)r * 128 + c0) = o;
    }
}

// ---------------------------------------------------------------------------
// Z[n,120] = h1[n,128] @ Bcat[128,120], Bcat[k][hop*40+j] = W2[(hop*128+k)*40+j]
// cols 80..119 (hop2) scaled by norm[row]. block=256: 8 rows x 120 cols.
// ---------------------------------------------------------------------------
__global__ __launch_bounds__(256) void gemm120_k(
    const float* __restrict__ A, const float* __restrict__ W2, float* __restrict__ Z,
    const float* __restrict__ norm, int n) {
    __shared__ float Bs[128 * 120];
    for (int i = threadIdx.x; i < 128 * 120; i += 256) {
        int k = i / 120, c = i % 120;
        int hop = c / 40, j = c - hop * 40;
        Bs[i] = W2[(size_t)(hop * 128 + k) * 40 + j];
    }
    __syncthreads();

    int lane = threadIdx.x & 63;
    int wave = threadIdx.x >> 6;
    int c = (wave & 1) * 64 + lane;
    bool active = c < 120;
    int cc = active ? c : 119;
    int r0 = blockIdx.x * 8 + (wave >> 1) * 4;

    int rA[4];
#pragma unroll
    for (int rr = 0; rr < 4; ++rr) rA[rr] = min(r0 + rr, n - 1);

    float acc[4] = {0, 0, 0, 0};
    for (int k = 0; k < 128; k += 4) {
        float4 av[4];
#pragma unroll
        for (int rr = 0; rr < 4; ++rr)
            av[rr] = *(const float4*)(A + (size_t)rA[rr] * 128 + k);
#pragma unroll
        for (int kk = 0; kk < 4; ++kk) {
            float b = Bs[(k + kk) * 120 + cc];
#pragma unroll
            for (int rr = 0; rr < 4; ++rr)
                acc[rr] = fmaf(((const float*)&av[rr])[kk], b, acc[rr]);
        }
    }
    if (active) {
#pragma unroll
        for (int rr = 0; rr < 4; ++rr) {
            int r = r0 + rr;
            if (r >= n) break;
            float v = acc[rr];
            if (c >= 80) v *= norm[r];
            Z[(size_t)r * 120 + c] = v;
        }
    }
}

// out[n,:] = sum_{e in in(n)} in[src(e),:]   (d=128, pure gather-sum)
__global__ __launch_bounds__(256) void spmm128_k(
    const float* __restrict__ in, float* __restrict__ out,
    const int* __restrict__ rowptr, const int* __restrict__ esrc, int n) {
    int gw = (blockIdx.x * 256 + threadIdx.x) >> 6;
    int lane = threadIdx.x & 63;
    if (gw >= n) return;
    int beg = rowptr[gw], end = rowptr[gw + 1];
    float a0 = 0.f, a1 = 0.f;
    int e = beg;
    for (; e + 3 < end; e += 4) {
        int s0 = esrc[e], s1 = esrc[e + 1], s2 = esrc[e + 2], s3 = esrc[e + 3];
        float2 v0 = *(const float2*)(in + (size_t)s0 * 128 + lane * 2);
        float2 v1 = *(const float2*)(in + (size_t)s1 * 128 + lane * 2);
        float2 v2 = *(const float2*)(in + (size_t)s2 * 128 + lane * 2);
        float2 v3 = *(const float2*)(in + (size_t)s3 * 128 + lane * 2);
        a0 += (v0.x + v1.x) + (v2.x + v3.x);
        a1 += (v0.y + v1.y) + (v2.y + v3.y);
    }
    for (; e < end; ++e) {
        int s = esrc[e];
        float2 v = *(const float2*)(in + (size_t)s * 128 + lane * 2);
        a0 += v.x;
        a1 += v.y;
    }
    float2 o; o.x = a0; o.y = a1;
    *(float2*)(out + (size_t)gw * 128 + lane * 2) = o;
}

// u'[n,j] = norm[n]*(Z[n,40+j] + norm[n]*sum_e Z[src(e),80+j]),  j<40
__global__ __launch_bounds__(256) void spmm40_k(
    const float* __restrict__ Z, float* __restrict__ u,
    const float* __restrict__ norm, const int* __restrict__ rowptr,
    const int* __restrict__ esrc, int n) {
    int gw = (blockIdx.x * 256 + threadIdx.x) >> 6;
    int lane = threadIdx.x & 63;
    if (gw >= n || lane >= 40) return;
    int beg = rowptr[gw], end = rowptr[gw + 1];
    float a = 0.f;
    int e = beg;
    for (; e + 3 < end; e += 4) {
        int s0 = esrc[e], s1 = esrc[e + 1], s2 = esrc[e + 2], s3 = esrc[e + 3];
        float v0 = Z[(size_t)s0 * 120 + 80 + lane];
        float v1 = Z[(size_t)s1 * 120 + 80 + lane];
        float v2 = Z[(size_t)s2 * 120 + 80 + lane];
        float v3 = Z[(size_t)s3 * 120 + 80 + lane];
        a += (v0 + v1) + (v2 + v3);
    }
    for (; e < end; ++e) a += Z[(size_t)esrc[e] * 120 + 80 + lane];
    float nn = norm[gw];
    u[(size_t)gw * 40 + lane] = nn * (Z[(size_t)gw * 120 + 40 + lane] + nn * a);
}

// r = relu(Z[n,0:40] + norm[n]*sum_e u'[src(e),:] + b2); partial-sum for mean
__global__ __launch_bounds__(256) void spmm40_final_k(
    const float* __restrict__ u, const float* __restrict__ Z, const float* __restrict__ bias,
    float* __restrict__ partial, const float* __restrict__ norm,
    const int* __restrict__ rowptr, const int* __restrict__ esrc, int n, int nwaves) {
    __shared__ float lds[4][40];
    int wave = threadIdx.x >> 6;
    int lane = threadIdx.x & 63;
    int gw0 = blockIdx.x * 4 + wave;
    float accm = 0.f;
    float bb = (lane < 40) ? bias[lane] : 0.f;
    for (int node = gw0; node < n; node += nwaves) {
        if (lane < 40) {
            int beg = rowptr[node], end = rowptr[node + 1];
            float a = 0.f;
            int e = beg;
            for (; e + 3 < end; e += 4) {
                int s0 = esrc[e], s1 = esrc[e + 1], s2 = esrc[e + 2], s3 = esrc[e + 3];
                float v0 = u[(size_t)s0 * 40 + lane];
                float v1 = u[(size_t)s1 * 40 + lane];
                float v2 = u[(size_t)s2 * 40 + lane];
                float v3 = u[(size_t)s3 * 40 + lane];
                a += (v0 + v1) + (v2 + v3);
            }
            for (; e < end; ++e) a += u[(size_t)esrc[e] * 40 + lane];
            float r = Z[(size_t)node * 120 + lane] + norm[node] * a + bb;
            accm += fmaxf(r, 0.f);
        }
    }
    if (lane < 40) lds[wave][lane] = accm;
    __syncthreads();
    if (threadIdx.x < 40) {
        partial[blockIdx.x * 40 + threadIdx.x] =
            lds[0][threadIdx.x] + lds[1][threadIdx.x] + lds[2][threadIdx.x] + lds[3][threadIdx.x];
    }
}

// out[c] = (1/N) * sum_b partial[b*40+c]; grid = 40 blocks
__global__ __launch_bounds__(256) void reduce_mean_k(
    const float* __restrict__ partial, float* __restrict__ out, int nb, float invN) {
    __shared__ float lds[256];
    int c = blockIdx.x, t = threadIdx.x;
    float s = 0.f;
    for (int i = t; i < nb; i += 256) s += partial[(size_t)i * 40 + c];
    lds[t] = s;
    __syncthreads();
    for (int o = 128; o > 0; o >>= 1) {
        if (t < o) lds[t] += lds[t + o];
        __syncthreads();
    }
    if (t == 0) out[c] = lds[0] * invN;
}

extern "C" void kernel_launch(void* const* d_in, const int* in_sizes, int n_in,
                              void* d_out, int out_size, void* d_ws, size_t ws_size,
                              hipStream_t stream) {
    const float* X   = (const float*)d_in[0];
    const int*   src = (const int*)d_in[1];
    const int*   dst = (const int*)d_in[2];
    const float* W1  = (const float*)d_in[3];
    const float* b1  = (const float*)d_in[4];
    const float* W2  = (const float*)d_in[5];
    const float* b2  = (const float*)d_in[6];
    float* out = (float*)d_out;

    const int IN = 128;
    const int N = in_sizes[0] / IN;
    const int E = in_sizes[1];

    char* w = (char*)d_ws;
    size_t off = 0;
    auto alloc = [&](size_t bytes) -> char* {
        char* p = w + off;
        off = (off + bytes + 15) & ~(size_t)15;
        return p;
    };
    float* norm    = (float*)alloc((size_t)N * 4);
    int*   deg     = (int*)alloc((size_t)N * 4);
    int*   rowptr  = (int*)alloc((size_t)(N + 1) * 4);
    int*   cursor  = (int*)alloc((size_t)N * 4);
    int*   bsum    = (int*)alloc(1024 * 4);
    int*   esrc    = (int*)alloc((size_t)E * 4);
    float* bufA    = (float*)alloc((size_t)N * 128 * 4);  // reused as Z[N][120]
    float* bufB    = (float*)alloc((size_t)N * 128 * 4);  // reused as u'[N][40]
    float* partial = (float*)alloc(2048 * 40 * 4);

    int nb_scan = (N + 1023) / 1024;

    // ---- graph preprocessing: degree, norm, CSR by dst ----
    zero_int_k<<<(N + 255) / 256, 256, 0, stream>>>(deg, N);
    edge_deg_k<<<(E + 255) / 256, 256, 0, stream>>>(dst, deg, E);
    norm_k<<<(N + 255) / 256, 256, 0, stream>>>(deg, norm, N);
    scan1_k<<<nb_scan, 256, 0, stream>>>(deg, rowptr, bsum, N);
    scan2_k<<<1, 64, 0, stream>>>(bsum, nb_scan);
    scan3_k<<<nb_scan, 256, 0, stream>>>(rowptr, cursor, bsum, N, E);
    scatter_k<<<(E + 255) / 256, 256, 0, stream>>>(src, dst, cursor, esrc, E);

    int gemm_grid = (N + 15) / 16;
    int spmm_grid = (N + 3) / 4;

    // ---- layer 1: h1 = relu(X@W0 + A(X@W1 + A(X@W2)) + b1) ----
    gemm128_k<1><<<gemm_grid, 256, 0, stream>>>(
        X, W1 + 2 * 128 * 128, bufA, nullptr, nullptr, norm, N);     // bufA = n.XW2
    spmm128_k<<<spmm_grid, 256, 0, stream>>>(bufA, bufB, rowptr, esrc, N);  // bufB = t
    gemm128_k<2><<<gemm_grid, 256, 0, stream>>>(
        X, W1 + 1 * 128 * 128, bufB, bufB, nullptr, norm, N);        // bufB = n.(XW1+n.t)
    spmm128_k<<<spmm_grid, 256, 0, stream>>>(bufB, bufA, rowptr, esrc, N);  // bufA = t2
    gemm128_k<3><<<gemm_grid, 256, 0, stream>>>(
        X, W1, bufB, bufA, b1, norm, N);                             // bufB = h1

    // ---- layer 2: out = mean(relu(Z0 + A(Z1 + A(Z2)) + b2)) ----
    float* Z = bufA;   // [N][120]: hop0 | hop1 | norm.hop2
    float* u = bufB;   // [N][40]
    gemm120_k<<<(N + 7) / 8, 256, 0, stream>>>(bufB, W2, Z, norm, N);
    spmm40_k<<<spmm_grid, 256, 0, stream>>>(Z, u, norm, rowptr, esrc, N);
    spmm40_final_k<<<2048, 256, 0, stream>>>(u, Z, b2, partial, norm, rowptr, esrc, N, 8192);
    reduce_mean_k<<<40, 256, 0, stream>>>(partial, out, 2048, 1.f / (float)N);
}

// Round 3
// 855.482 us; speedup vs baseline: 3.3514x; 2.5614x over previous
//
#include <hip/hip_runtime.h>

// ---------------------------------------------------------------------------
// TAGConv (K=2) x2 + mean pool.
//   concat([h, Ah, A^2 h]) @ [W0;W1;W2] + b = h@W0 + A(h@W1 + A(h@W2)) + b
// D^{-1/2} folded into GEMM epilogues -> SpMMs are pure gather-sums.
// GEMM: 64 rows/block, B staged in 2x (64x128) LDS chunks (32KB -> 5 blk/CU),
//       4 rows x 8 cols register tile per thread.
// ---------------------------------------------------------------------------

__global__ void zero_int_k(int* __restrict__ p, int n) {
    int i = blockIdx.x * 256 + threadIdx.x;
    if (i < n) p[i] = 0;
}

__global__ void edge_deg_k(const int* __restrict__ dst, int* __restrict__ deg, int E) {
    int e = blockIdx.x * 256 + threadIdx.x;
    if (e < E) atomicAdd(&deg[dst[e]], 1);
}

__global__ void norm_k(const int* __restrict__ deg, float* __restrict__ norm, int n) {
    int i = blockIdx.x * 256 + threadIdx.x;
    if (i < n) {
        int d = deg[i];
        norm[i] = (d > 0) ? rsqrtf((float)d) : 0.f;
    }
}

// exclusive scan of deg -> rowptr
__global__ void scan1_k(const int* __restrict__ deg, int* __restrict__ rowptr,
                        int* __restrict__ bsum, int n) {
    __shared__ int lds[256];
    int t = threadIdx.x;
    int base = blockIdx.x * 1024 + t * 4;
    int v[4];
    int s = 0;
#pragma unroll
    for (int i = 0; i < 4; ++i) {
        v[i] = s;
        int idx = base + i;
        s += (idx < n) ? deg[idx] : 0;
    }
    int x = s;
    lds[t] = x;
    __syncthreads();
    for (int off = 1; off < 256; off <<= 1) {
        int y = (t >= off) ? lds[t - off] : 0;
        __syncthreads();
        x += y;
        lds[t] = x;
        __syncthreads();
    }
    int toff = x - s;
    if (t == 255) bsum[blockIdx.x] = x;
#pragma unroll
    for (int i = 0; i < 4; ++i) {
        int idx = base + i;
        if (idx < n) rowptr[idx] = toff + v[i];
    }
}

__global__ void scan2_k(int* __restrict__ bsum, int nb) {
    if (blockIdx.x == 0 && threadIdx.x == 0) {
        int run = 0;
        for (int i = 0; i < nb; ++i) { int t = bsum[i]; bsum[i] = run; run += t; }
    }
}

__global__ void scan3_k(int* __restrict__ rowptr, int* __restrict__ cursor,
                        const int* __restrict__ bsum, int n, int E) {
    int t = threadIdx.x;
    int base = blockIdx.x * 1024 + t * 4;
    int boff = bsum[blockIdx.x];
#pragma unroll
    for (int i = 0; i < 4; ++i) {
        int idx = base + i;
        if (idx < n) {
            int v = rowptr[idx] + boff;
            rowptr[idx] = v;
            cursor[idx] = v;
        }
    }
    if (blockIdx.x == 0 && t == 0) rowptr[n] = E;
}

__global__ void scatter_k(const int* __restrict__ src, const int* __restrict__ dst,
                          int* __restrict__ cursor, int* __restrict__ esrc, int E) {
    int e = blockIdx.x * 256 + threadIdx.x;
    if (e < E) {
        int p = atomicAdd(&cursor[dst[e]], 1);
        esrc[p] = src[e];
    }
}

// ---------------------------------------------------------------------------
// C[n,M] = A[n,128] @ B  (B layout per M), with norm-folding epilogues.
// M=128: B is [128][128].  MODE 1: C=norm*dot
//                          MODE 2: C=norm*(dot+norm*addp)  (in-place ok)
//                          MODE 3: C=relu(dot+norm*addp+bias)
// M=120: B is W2 [3][128][40] -> cols hop*40+j; MODE 0: cols>=80 scaled by norm
// block=256: 4 waves x 16 rows = 64 rows; thread tile 4 rows x 8 cols.
// ---------------------------------------------------------------------------
template <int M, int MODE>
__global__ __launch_bounds__(256) void gemm_k(
    const float* __restrict__ A, const float* __restrict__ B, float* __restrict__ C,
    const float* __restrict__ addp, const float* __restrict__ bias,
    const float* __restrict__ norm, int n) {
    __shared__ float Bs[64 * 128];  // 32 KB

    int lane = threadIdx.x & 63;
    int wave = threadIdx.x >> 6;
    int c0 = (lane & 15) * 8;
    int r0 = blockIdx.x * 64 + wave * 16 + (lane >> 4) * 4;

    int rA[4];
#pragma unroll
    for (int rr = 0; rr < 4; ++rr) rA[rr] = min(r0 + rr, n - 1);

    float acc[4][8];
#pragma unroll
    for (int rr = 0; rr < 4; ++rr)
#pragma unroll
        for (int j = 0; j < 8; ++j) acc[rr][j] = 0.f;

    for (int kc = 0; kc < 2; ++kc) {
        if (kc) __syncthreads();
        if (M == 128) {
            const float4* Bg = (const float4*)(B + kc * 64 * 128);
            for (int i = threadIdx.x; i < 64 * 128 / 4; i += 256)
                ((float4*)Bs)[i] = Bg[i];
        } else {  // M == 120: gather from W2[3][128][40], pad cols 120..127 with 0
            for (int i = threadIdx.x; i < 2048; i += 256) {
                if (i < 1920) {
                    int k = i / 30, rem = i % 30;
                    int hop = rem / 10, j4 = rem - hop * 10;
                    *(float4*)&Bs[k * 128 + hop * 40 + j4 * 4] =
                        *(const float4*)(B + ((size_t)(hop * 128 + kc * 64 + k) * 40 + j4 * 4));
                } else {
                    int j = i - 1920;
                    int k = j >> 1, q = j & 1;
                    float4 z; z.x = 0.f; z.y = 0.f; z.z = 0.f; z.w = 0.f;
                    *(float4*)&Bs[k * 128 + 120 + q * 4] = z;
                }
            }
        }
        __syncthreads();

        const float* Ab = A + kc * 64;
#pragma unroll 2
        for (int k4 = 0; k4 < 16; ++k4) {
            float4 av[4];
#pragma unroll
            for (int rr = 0; rr < 4; ++rr)
                av[rr] = *(const float4*)(Ab + (size_t)rA[rr] * 128 + k4 * 4);
#pragma unroll
            for (int kk = 0; kk < 4; ++kk) {
                float4 b0 = *(const float4*)&Bs[(k4 * 4 + kk) * 128 + c0];
                float4 b1 = *(const float4*)&Bs[(k4 * 4 + kk) * 128 + c0 + 4];
#pragma unroll
                for (int rr = 0; rr < 4; ++rr) {
                    float a = ((const float*)&av[rr])[kk];
                    acc[rr][0] = fmaf(a, b0.x, acc[rr][0]);
                    acc[rr][1] = fmaf(a, b0.y, acc[rr][1]);
                    acc[rr][2] = fmaf(a, b0.z, acc[rr][2]);
                    acc[rr][3] = fmaf(a, b0.w, acc[rr][3]);
                    acc[rr][4] = fmaf(a, b1.x, acc[rr][4]);
                    acc[rr][5] = fmaf(a, b1.y, acc[rr][5]);
                    acc[rr][6] = fmaf(a, b1.z, acc[rr][6]);
                    acc[rr][7] = fmaf(a, b1.w, acc[rr][7]);
                }
            }
        }
    }

    float bb[8];
    if (MODE == 3) {
#pragma unroll
        for (int j = 0; j < 8; ++j) bb[j] = bias[c0 + j];
    }

#pragma unroll
    for (int rr = 0; rr < 4; ++rr) {
        int r = r0 + rr;
        if (r >= n) break;
        float nr = norm[r];
        float o[8];
#pragma unroll
        for (int j = 0; j < 8; ++j) o[j] = acc[rr][j];

        if (MODE == 0) {  // M=120 layer-2 combined GEMM
            if (c0 >= 120) continue;
            if (c0 >= 80) {
#pragma unroll
                for (int j = 0; j < 8; ++j) o[j] *= nr;
            }
            float4 o0; o0.x = o[0]; o0.y = o[1]; o0.z = o[2]; o0.w = o[3];
            float4 o1; o1.x = o[4]; o1.y = o[5]; o1.z = o[6]; o1.w = o[7];
            *(float4*)(C + (size_t)r * 120 + c0) = o0;
            *(float4*)(C + (size_t)r * 120 + c0 + 4) = o1;
            continue;
        }
        if (MODE == 1) {
#pragma unroll
            for (int j = 0; j < 8; ++j) o[j] *= nr;
        }
        if (MODE == 2) {
            float4 a0 = *(const float4*)(addp + (size_t)r * 128 + c0);
            float4 a1 = *(const float4*)(addp + (size_t)r * 128 + c0 + 4);
            const float* ap = (const float*)&a0;
#pragma unroll
            for (int j = 0; j < 4; ++j) o[j] = nr * (o[j] + nr * ap[j]);
            ap = (const float*)&a1;
#pragma unroll
            for (int j = 0; j < 4; ++j) o[4 + j] = nr * (o[4 + j] + nr * ap[j]);
        }
        if (MODE == 3) {
            float4 a0 = *(const float4*)(addp + (size_t)r * 128 + c0);
            float4 a1 = *(const float4*)(addp + (size_t)r * 128 + c0 + 4);
            const float* ap = (const float*)&a0;
#pragma unroll
            for (int j = 0; j < 4; ++j) o[j] = fmaxf(o[j] + nr * ap[j] + bb[j], 0.f);
            ap = (const float*)&a1;
#pragma unroll
            for (int j = 0; j < 4; ++j) o[4 + j] = fmaxf(o[4 + j] + nr * ap[j] + bb[4 + j], 0.f);
        }
        float4 o0; o0.x = o[0]; o0.y = o[1]; o0.z = o[2]; o0.w = o[3];
        float4 o1; o1.x = o[4]; o1.y = o[5]; o1.z = o[6]; o1.w = o[7];
        *(float4*)(C + (size_t)r * 128 + c0) = o0;
        *(float4*)(C + (size_t)r * 128 + c0 + 4) = o1;
    }
}

// out[n,:] = sum_{e in in(n)} in[src(e),:]  (d=128). One wave per node,
// 2 edges in parallel (half-wave x float4), 2-pair unroll.
__global__ __launch_bounds__(256) void spmm128_k(
    const float* __restrict__ in, float* __restrict__ out,
    const int* __restrict__ rowptr, const int* __restrict__ esrc, int n) {
    int gw = (blockIdx.x * 256 + threadIdx.x) >> 6;
    if (gw >= n) return;
    int lane = threadIdx.x & 63;
    int sub = lane >> 5, l32 = lane & 31;
    int beg = rowptr[gw], end = rowptr[gw + 1];
    float4 a; a.x = 0.f; a.y = 0.f; a.z = 0.f; a.w = 0.f;
    int e = beg + sub;
    for (; e + 2 < end; e += 4) {
        int s0 = esrc[e], s1 = esrc[e + 2];
        float4 v0 = *(const float4*)(in + (size_t)s0 * 128 + l32 * 4);
        float4 v1 = *(const float4*)(in + (size_t)s1 * 128 + l32 * 4);
        a.x += v0.x + v1.x;
        a.y += v0.y + v1.y;
        a.z += v0.z + v1.z;
        a.w += v0.w + v1.w;
    }
    for (; e < end; e += 2) {
        int s = esrc[e];
        float4 v = *(const float4*)(in + (size_t)s * 128 + l32 * 4);
        a.x += v.x; a.y += v.y; a.z += v.z; a.w += v.w;
    }
    a.x += __shfl_xor(a.x, 32);
    a.y += __shfl_xor(a.y, 32);
    a.z += __shfl_xor(a.z, 32);
    a.w += __shfl_xor(a.w, 32);
    if (sub == 0) *(float4*)(out + (size_t)gw * 128 + l32 * 4) = a;
}

// u'[n,j] = norm[n]*(Z[n,40+j] + norm[n]*sum_e Z[src(e),80+j]),  j<40
__global__ __launch_bounds__(256) void spmm40_k(
    const float* __restrict__ Z, float* __restrict__ u,
    const float* __restrict__ norm, const int* __restrict__ rowptr,
    const int* __restrict__ esrc, int n) {
    int gw = (blockIdx.x * 256 + threadIdx.x) >> 6;
    int lane = threadIdx.x & 63;
    if (gw >= n || lane >= 40) return;
    int beg = rowptr[gw], end = rowptr[gw + 1];
    float a = 0.f;
    int e = beg;
    for (; e + 3 < end; e += 4) {
        int s0 = esrc[e], s1 = esrc[e + 1], s2 = esrc[e + 2], s3 = esrc[e + 3];
        float v0 = Z[(size_t)s0 * 120 + 80 + lane];
        float v1 = Z[(size_t)s1 * 120 + 80 + lane];
        float v2 = Z[(size_t)s2 * 120 + 80 + lane];
        float v3 = Z[(size_t)s3 * 120 + 80 + lane];
        a += (v0 + v1) + (v2 + v3);
    }
    for (; e < end; ++e) a += Z[(size_t)esrc[e] * 120 + 80 + lane];
    float nn = norm[gw];
    u[(size_t)gw * 40 + lane] = nn * (Z[(size_t)gw * 120 + 40 + lane] + nn * a);
}

// r = relu(Z[n,0:40] + norm[n]*sum_e u'[src(e),:] + b2); partial-sum for mean
__global__ __launch_bounds__(256) void spmm40_final_k(
    const float* __restrict__ u, const float* __restrict__ Z, const float* __restrict__ bias,
    float* __restrict__ partial, const float* __restrict__ norm,
    const int* __restrict__ rowptr, const int* __restrict__ esrc, int n, int nwaves) {
    __shared__ float lds[4][40];
    int wave = threadIdx.x >> 6;
    int lane = threadIdx.x & 63;
    int gw0 = blockIdx.x * 4 + wave;
    float accm = 0.f;
    float bb = (lane < 40) ? bias[lane] : 0.f;
    for (int node = gw0; node < n; node += nwaves) {
        if (lane < 40) {
            int beg = rowptr[node], end = rowptr[node + 1];
            float a = 0.f;
            int e = beg;
            for (; e + 3 < end; e += 4) {
                int s0 = esrc[e], s1 = esrc[e + 1], s2 = esrc[e + 2], s3 = esrc[e + 3];
                float v0 = u[(size_t)s0 * 40 + lane];
                float v1 = u[(size_t)s1 * 40 + lane];
                float v2 = u[(size_t)s2 * 40 + lane];
                float v3 = u[(size_t)s3 * 40 + lane];
                a += (v0 + v1) + (v2 + v3);
            }
            for (; e < end; ++e) a += u[(size_t)esrc[e] * 40 + lane];
            float r = Z[(size_t)node * 120 + lane] + norm[node] * a + bb;
            accm += fmaxf(r, 0.f);
        }
    }
    if (lane < 40) lds[wave][lane] = accm;
    __syncthreads();
    if (threadIdx.x < 40) {
        partial[blockIdx.x * 40 + threadIdx.x] =
            lds[0][threadIdx.x] + lds[1][threadIdx.x] + lds[2][threadIdx.x] + lds[3][threadIdx.x];
    }
}

__global__ __launch_bounds__(256) void reduce_mean_k(
    const float* __restrict__ partial, float* __restrict__ out, int nb, float invN) {
    __shared__ float lds[256];
    int c = blockIdx.x, t = threadIdx.x;
    float s = 0.f;
    for (int i = t; i < nb; i += 256) s += partial[(size_t)i * 40 + c];
    lds[t] = s;
    __syncthreads();
    for (int o = 128; o > 0; o >>= 1) {
        if (t < o) lds[t] += lds[t + o];
        __syncthreads();
    }
    if (t == 0) out[c] = lds[0] * invN;
}

extern "C" void kernel_launch(void* const* d_in, const int* in_sizes, int n_in,
                              void* d_out, int out_size, void* d_ws, size_t ws_size,
                              hipStream_t stream) {
    const float* X   = (const float*)d_in[0];
    const int*   src = (const int*)d_in[1];
    const int*   dst = (const int*)d_in[2];
    const float* W1  = (const float*)d_in[3];
    const float* b1  = (const float*)d_in[4];
    const float* W2  = (const float*)d_in[5];
    const float* b2  = (const float*)d_in[6];
    float* out = (float*)d_out;

    const int IN = 128;
    const int N = in_sizes[0] / IN;
    const int E = in_sizes[1];

    char* w = (char*)d_ws;
    size_t off = 0;
    auto alloc = [&](size_t bytes) -> char* {
        char* p = w + off;
        off = (off + bytes + 15) & ~(size_t)15;
        return p;
    };
    float* norm    = (float*)alloc((size_t)N * 4);
    int*   deg     = (int*)alloc((size_t)N * 4);
    int*   rowptr  = (int*)alloc((size_t)(N + 1) * 4);
    int*   cursor  = (int*)alloc((size_t)N * 4);
    int*   bsum    = (int*)alloc(1024 * 4);
    int*   esrc    = (int*)alloc((size_t)E * 4);
    float* bufA    = (float*)alloc((size_t)N * 128 * 4);  // reused as Z[N][120]
    float* bufB    = (float*)alloc((size_t)N * 128 * 4);  // reused as u'[N][40]
    float* partial = (float*)alloc(2048 * 40 * 4);

    int nb_scan = (N + 1023) / 1024;

    zero_int_k<<<(N + 255) / 256, 256, 0, stream>>>(deg, N);
    edge_deg_k<<<(E + 255) / 256, 256, 0, stream>>>(dst, deg, E);
    norm_k<<<(N + 255) / 256, 256, 0, stream>>>(deg, norm, N);
    scan1_k<<<nb_scan, 256, 0, stream>>>(deg, rowptr, bsum, N);
    scan2_k<<<1, 64, 0, stream>>>(bsum, nb_scan);
    scan3_k<<<nb_scan, 256, 0, stream>>>(rowptr, cursor, bsum, N, E);
    scatter_k<<<(E + 255) / 256, 256, 0, stream>>>(src, dst, cursor, esrc, E);

    int gemm_grid = (N + 63) / 64;
    int spmm_grid = (N + 3) / 4;

    // ---- layer 1: h1 = relu(X@W0 + A(X@W1 + A(X@W2)) + b1) ----
    gemm_k<128, 1><<<gemm_grid, 256, 0, stream>>>(
        X, W1 + 2 * 128 * 128, bufA, nullptr, nullptr, norm, N);
    spmm128_k<<<spmm_grid, 256, 0, stream>>>(bufA, bufB, rowptr, esrc, N);
    gemm_k<128, 2><<<gemm_grid, 256, 0, stream>>>(
        X, W1 + 1 * 128 * 128, bufB, bufB, nullptr, norm, N);
    spmm128_k<<<spmm_grid, 256, 0, stream>>>(bufB, bufA, rowptr, esrc, N);
    gemm_k<128, 3><<<gemm_grid, 256, 0, stream>>>(
        X, W1, bufB, bufA, b1, norm, N);   // bufB = h1

    // ---- layer 2: out = mean(relu(Z0 + A(Z1 + A(Z2)) + b2)) ----
    float* Z = bufA;   // [N][120]: hop0 | hop1 | norm*hop2
    float* u = bufB;   // [N][40]
    gemm_k<120, 0><<<gemm_grid, 256, 0, stream>>>(
        bufB, W2, Z, nullptr, nullptr, norm, N);
    spmm40_k<<<spmm_grid, 256, 0, stream>>>(Z, u, norm, rowptr, esrc, N);
    spmm40_final_k<<<2048, 256, 0, stream>>>(u, Z, b2, partial, norm, rowptr, esrc, N, 8192);
    reduce_mean_k<<<40, 256, 0, stream>>>(partial, out, 2048, 1.f / (float)N);
}

// Round 4
// 733.211 us; speedup vs baseline: 3.9103x; 1.1668x over previous
//
#include <hip/hip_runtime.h>

typedef unsigned short u16;
typedef __attribute__((ext_vector_type(8))) short bf16x8;
typedef __attribute__((ext_vector_type(4))) float f32x4;

__device__ inline u16 f2bf(float f) {
    union { float f; unsigned u; } v; v.f = f;
    unsigned r = v.u + 0x7fff + ((v.u >> 16) & 1);
    return (u16)(r >> 16);
}

// ---------------------------------------------------------------------------
// graph preprocessing
// ---------------------------------------------------------------------------
__global__ void zero_int_k(int* __restrict__ p, int n) {
    int i = blockIdx.x * 256 + threadIdx.x;
    if (i < n) p[i] = 0;
}

__global__ void edge_deg_k(const int* __restrict__ dst, int* __restrict__ deg, int E) {
    int e = blockIdx.x * 256 + threadIdx.x;
    if (e < E) atomicAdd(&deg[dst[e]], 1);
}

__global__ void norm_k(const int* __restrict__ deg, float* __restrict__ norm, int n) {
    int i = blockIdx.x * 256 + threadIdx.x;
    if (i < n) {
        int d = deg[i];
        norm[i] = (d > 0) ? rsqrtf((float)d) : 0.f;
    }
}

__global__ void scan1_k(const int* __restrict__ deg, int* __restrict__ rowptr,
                        int* __restrict__ bsum, int n) {
    __shared__ int lds[256];
    int t = threadIdx.x;
    int base = blockIdx.x * 1024 + t * 4;
    int v[4];
    int s = 0;
#pragma unroll
    for (int i = 0; i < 4; ++i) {
        v[i] = s;
        int idx = base + i;
        s += (idx < n) ? deg[idx] : 0;
    }
    int x = s;
    lds[t] = x;
    __syncthreads();
    for (int off = 1; off < 256; off <<= 1) {
        int y = (t >= off) ? lds[t - off] : 0;
        __syncthreads();
        x += y;
        lds[t] = x;
        __syncthreads();
    }
    int toff = x - s;
    if (t == 255) bsum[blockIdx.x] = x;
#pragma unroll
    for (int i = 0; i < 4; ++i) {
        int idx = base + i;
        if (idx < n) rowptr[idx] = toff + v[i];
    }
}

__global__ void scan2_k(int* __restrict__ bsum, int nb) {
    if (blockIdx.x == 0 && threadIdx.x == 0) {
        int run = 0;
        for (int i = 0; i < nb; ++i) { int t = bsum[i]; bsum[i] = run; run += t; }
    }
}

__global__ void scan3_k(int* __restrict__ rowptr, int* __restrict__ cursor,
                        const int* __restrict__ bsum, int n, int E) {
    int t = threadIdx.x;
    int base = blockIdx.x * 1024 + t * 4;
    int boff = bsum[blockIdx.x];
#pragma unroll
    for (int i = 0; i < 4; ++i) {
        int idx = base + i;
        if (idx < n) {
            int v = rowptr[idx] + boff;
            rowptr[idx] = v;
            cursor[idx] = v;
        }
    }
    if (blockIdx.x == 0 && t == 0) rowptr[n] = E;
}

__global__ void scatter_k(const int* __restrict__ src, const int* __restrict__ dst,
                          int* __restrict__ cursor, int* __restrict__ esrc, int E) {
    int e = blockIdx.x * 256 + threadIdx.x;
    if (e < E) {
        int p = atomicAdd(&cursor[dst[e]], 1);
        esrc[p] = src[e];
    }
}

// ---------------------------------------------------------------------------
// prep: X -> bf16; W -> MFMA-fragment-packed bf16.
// Wp[((t*4+kk)*64+lane)*8+jj] = B[k][c], k = kk*32+(lane>>4)*8+jj, c = t*16+(lane&15)
// ---------------------------------------------------------------------------
__global__ void cvt_x_k(const float* __restrict__ X, u16* __restrict__ Xb, long n4) {
    long i = (long)blockIdx.x * 256 + threadIdx.x;
    if (i >= n4) return;
    float4 v = ((const float4*)X)[i];
    ushort4 o;
    o.x = f2bf(v.x); o.y = f2bf(v.y); o.z = f2bf(v.z); o.w = f2bf(v.w);
    ((ushort4*)Xb)[i] = o;
}

__global__ void pack_w1_k(const float* __restrict__ W1, u16* __restrict__ Wp) {
    int i = blockIdx.x * 256 + threadIdx.x;
    if (i >= 3 * 16384) return;
    int m = i >> 14, r = i & 16383;
    int jj = r & 7, lane = (r >> 3) & 63, kk = (r >> 9) & 3, t = r >> 11;
    int k = kk * 32 + (lane >> 4) * 8 + jj;
    int c = t * 16 + (lane & 15);
    Wp[i] = f2bf(W1[(size_t)m * 16384 + k * 128 + c]);
}

__global__ void pack_w2_k(const float* __restrict__ W2, u16* __restrict__ Wp) {
    int i = blockIdx.x * 256 + threadIdx.x;
    if (i >= 16384) return;
    int jj = i & 7, lane = (i >> 3) & 63, kk = (i >> 9) & 3, t = i >> 11;
    int k = kk * 32 + (lane >> 4) * 8 + jj;
    int c = t * 16 + (lane & 15);
    float v = 0.f;
    if (c < 120) {
        int hop = c / 40, j = c - hop * 40;
        v = W2[(size_t)(hop * 128 + k) * 40 + j];
    }
    Wp[i] = f2bf(v);
}

// ---------------------------------------------------------------------------
// MFMA GEMM (see header comment in previous round). MODE 0/1/2/3.
// ---------------------------------------------------------------------------
template <int MODE>
__global__ __launch_bounds__(256, 2) void gemm_mfma_k(
    const u16* __restrict__ Ab, const u16* __restrict__ Wp,
    float* __restrict__ Cf, u16* __restrict__ Cb,
    const float* __restrict__ addp, const float* __restrict__ bias,
    const float* __restrict__ norm, int n, int nStripes) {
    int lane = threadIdx.x & 63;
    int wave = threadIdx.x >> 6;
    int rit = lane & 15;
    int kgrp = lane >> 4;

    bf16x8 bfr[8][4];
    const bf16x8* wp = (const bf16x8*)Wp;
#pragma unroll
    for (int t = 0; t < 8; ++t)
#pragma unroll
        for (int kk = 0; kk < 4; ++kk)
            bfr[t][kk] = wp[(t * 4 + kk) * 64 + lane];

    for (int s = blockIdx.x; s < nStripes; s += gridDim.x) {
        int r0 = s * 64 + wave * 16;
        int ar = min(r0 + rit, n - 1);
        const bf16x8* arow = (const bf16x8*)(Ab + (size_t)ar * 128);
        bf16x8 afr[4];
#pragma unroll
        for (int kk = 0; kk < 4; ++kk) afr[kk] = arow[kk * 4 + kgrp];

        f32x4 acc[8];
#pragma unroll
        for (int t = 0; t < 8; ++t) acc[t] = (f32x4)(0.f);
#pragma unroll
        for (int kk = 0; kk < 4; ++kk)
#pragma unroll
            for (int t = 0; t < 8; ++t)
                acc[t] = __builtin_amdgcn_mfma_f32_16x16x32_bf16(
                    afr[kk], bfr[t][kk], acc[t], 0, 0, 0);

#pragma unroll
        for (int j = 0; j < 4; ++j) {
            int rs = r0 + kgrp * 4 + j;
            if (rs >= n) continue;
            float nr = norm[rs];
#pragma unroll
            for (int t = 0; t < 8; ++t) {
                int c = t * 16 + rit;
                float v = acc[t][j];
                if (MODE == 0) {
                    if (c < 120) {
                        if (c >= 80) v *= nr;
                        Cf[(size_t)rs * 120 + c] = v;
                    }
                } else if (MODE == 1) {
                    Cf[(size_t)rs * 128 + c] = v * nr;
                } else if (MODE == 2) {
                    float ap = addp[(size_t)rs * 128 + c];
                    Cf[(size_t)rs * 128 + c] = nr * (v + nr * ap);
                } else {
                    float ap = addp[(size_t)rs * 128 + c];
                    float r = fmaxf(v + nr * ap + bias[c], 0.f);
                    Cb[(size_t)rs * 128 + c] = f2bf(r);
                }
            }
        }
    }
}

// out[n,:] = sum_{e in in(n)} in[src(e),:]  (d=128)
__global__ __launch_bounds__(256) void spmm128_k(
    const float* __restrict__ in, float* __restrict__ out,
    const int* __restrict__ rowptr, const int* __restrict__ esrc, int n) {
    int gw = (blockIdx.x * 256 + threadIdx.x) >> 6;
    if (gw >= n) return;
    int lane = threadIdx.x & 63;
    int sub = lane >> 5, l32 = lane & 31;
    int beg = rowptr[gw], end = rowptr[gw + 1];
    float4 a; a.x = 0.f; a.y = 0.f; a.z = 0.f; a.w = 0.f;
    int e = beg + sub;
    for (; e + 6 < end; e += 8) {
        int s0 = esrc[e], s1 = esrc[e + 2], s2 = esrc[e + 4], s3 = esrc[e + 6];
        float4 v0 = *(const float4*)(in + (size_t)s0 * 128 + l32 * 4);
        float4 v1 = *(const float4*)(in + (size_t)s1 * 128 + l32 * 4);
        float4 v2 = *(const float4*)(in + (size_t)s2 * 128 + l32 * 4);
        float4 v3 = *(const float4*)(in + (size_t)s3 * 128 + l32 * 4);
        a.x += (v0.x + v1.x) + (v2.x + v3.x);
        a.y += (v0.y + v1.y) + (v2.y + v3.y);
        a.z += (v0.z + v1.z) + (v2.z + v3.z);
        a.w += (v0.w + v1.w) + (v2.w + v3.w);
    }
    for (; e < end; e += 2) {
        int s = esrc[e];
        float4 v = *(const float4*)(in + (size_t)s * 128 + l32 * 4);
        a.x += v.x; a.y += v.y; a.z += v.z; a.w += v.w;
    }
    a.x += __shfl_xor(a.x, 32);
    a.y += __shfl_xor(a.y, 32);
    a.z += __shfl_xor(a.z, 32);
    a.w += __shfl_xor(a.w, 32);
    if (sub == 0) *(float4*)(out + (size_t)gw * 128 + l32 * 4) = a;
}

// u'[n,j] = norm[n]*(Z[n,40+j] + norm[n]*sum_e Z[src(e),80+j]),  j<40
__global__ __launch_bounds__(256) void spmm40_k(
    const float* __restrict__ Z, float* __restrict__ u,
    const float* __restrict__ norm, const int* __restrict__ rowptr,
    const int* __restrict__ esrc, int n) {
    int gw = (blockIdx.x * 256 + threadIdx.x) >> 6;
    int lane = threadIdx.x & 63;
    if (gw >= n || lane >= 40) return;
    int beg = rowptr[gw], end = rowptr[gw + 1];
    float a = 0.f;
    int e = beg;
    for (; e + 3 < end; e += 4) {
        int s0 = esrc[e], s1 = esrc[e + 1], s2 = esrc[e + 2], s3 = esrc[e + 3];
        float v0 = Z[(size_t)s0 * 120 + 80 + lane];
        float v1 = Z[(size_t)s1 * 120 + 80 + lane];
        float v2 = Z[(size_t)s2 * 120 + 80 + lane];
        float v3 = Z[(size_t)s3 * 120 + 80 + lane];
        a += (v0 + v1) + (v2 + v3);
    }
    for (; e < end; ++e) a += Z[(size_t)esrc[e] * 120 + 80 + lane];
    float nn = norm[gw];
    u[(size_t)gw * 40 + lane] = nn * (Z[(size_t)gw * 120 + 40 + lane] + nn * a);
}

// r = relu(Z[n,0:40] + norm[n]*sum_e u'[src(e),:] + b2); partial-sum for mean
__global__ __launch_bounds__(256) void spmm40_final_k(
    const float* __restrict__ u, const float* __restrict__ Z, const float* __restrict__ bias,
    float* __restrict__ partial, const float* __restrict__ norm,
    const int* __restrict__ rowptr, const int* __restrict__ esrc, int n, int nwaves) {
    __shared__ float lds[4][40];
    int wave = threadIdx.x >> 6;
    int lane = threadIdx.x & 63;
    int gw0 = blockIdx.x * 4 + wave;
    float accm = 0.f;
    float bb = (lane < 40) ? bias[lane] : 0.f;
    for (int node = gw0; node < n; node += nwaves) {
        if (lane < 40) {
            int beg = rowptr[node], end = rowptr[node + 1];
            float a = 0.f;
            int e = beg;
            for (; e + 3 < end; e += 4) {
                int s0 = esrc[e], s1 = esrc[e + 1], s2 = esrc[e + 2], s3 = esrc[e + 3];
                float v0 = u[(size_t)s0 * 40 + lane];
                float v1 = u[(size_t)s1 * 40 + lane];
                float v2 = u[(size_t)s2 * 40 + lane];
                float v3 = u[(size_t)s3 * 40 + lane];
                a += (v0 + v1) + (v2 + v3);
            }
            for (; e < end; ++e) a += u[(size_t)esrc[e] * 40 + lane];
            float r = Z[(size_t)node * 120 + lane] + norm[node] * a + bb;
            accm += fmaxf(r, 0.f);
        }
    }
    if (lane < 40) lds[wave][lane] = accm;
    __syncthreads();
    if (threadIdx.x < 40) {
        partial[blockIdx.x * 40 + threadIdx.x] =
            lds[0][threadIdx.x] + lds[1][threadIdx.x] + lds[2][threadIdx.x] + lds[3][threadIdx.x];
    }
}

__global__ __launch_bounds__(256) void reduce_mean_k(
    const float* __restrict__ partial, float* __restrict__ out, int nb, float invN) {
    __shared__ float lds[256];
    int c = blockIdx.x, t = threadIdx.x;
    float s = 0.f;
    for (int i = t; i < nb; i += 256) s += partial[(size_t)i * 40 + c];
    lds[t] = s;
    __syncthreads();
    for (int o = 128; o > 0; o >>= 1) {
        if (t < o) lds[t] += lds[t + o];
        __syncthreads();
    }
    if (t == 0) out[c] = lds[0] * invN;
}

extern "C" void kernel_launch(void* const* d_in, const int* in_sizes, int n_in,
                              void* d_out, int out_size, void* d_ws, size_t ws_size,
                              hipStream_t stream) {
    const float* X   = (const float*)d_in[0];
    const int*   src = (const int*)d_in[1];
    const int*   dst = (const int*)d_in[2];
    const float* W1  = (const float*)d_in[3];
    const float* b1  = (const float*)d_in[4];
    const float* W2  = (const float*)d_in[5];
    const float* b2  = (const float*)d_in[6];
    float* out = (float*)d_out;

    const int IN = 128;
    const int N = in_sizes[0] / IN;
    const int E = in_sizes[1];

    char* w = (char*)d_ws;
    size_t off = 0;
    auto alloc = [&](size_t bytes) -> char* {
        char* p = w + off;
        off = (off + bytes + 15) & ~(size_t)15;
        return p;
    };
    float* norm    = (float*)alloc((size_t)N * 4);
    int*   deg     = (int*)alloc((size_t)N * 4);
    int*   rowptr  = (int*)alloc((size_t)(N + 1) * 4);
    int*   cursor  = (int*)alloc((size_t)N * 4);
    int*   bsum    = (int*)alloc(1024 * 4);
    int*   esrc    = (int*)alloc((size_t)E * 4);
    u16*   Xb      = (u16*)alloc((size_t)N * 128 * 2);
    u16*   h1b     = (u16*)alloc((size_t)N * 128 * 2);
    u16*   Wp1     = (u16*)alloc(3 * 16384 * 2);
    u16*   Wp2     = (u16*)alloc(16384 * 2);
    float* bufA    = (float*)alloc((size_t)N * 128 * 4);
    float* bufB    = (float*)alloc((size_t)N * 128 * 4);
    float* partial = (float*)alloc(2048 * 40 * 4);

    int nb_scan = (N + 1023) / 1024;

    zero_int_k<<<(N + 255) / 256, 256, 0, stream>>>(deg, N);
    edge_deg_k<<<(E + 255) / 256, 256, 0, stream>>>(dst, deg, E);
    norm_k<<<(N + 255) / 256, 256, 0, stream>>>(deg, norm, N);
    scan1_k<<<nb_scan, 256, 0, stream>>>(deg, rowptr, bsum, N);
    scan2_k<<<1, 64, 0, stream>>>(bsum, nb_scan);
    scan3_k<<<nb_scan, 256, 0, stream>>>(rowptr, cursor, bsum, N, E);
    scatter_k<<<(E + 255) / 256, 256, 0, stream>>>(src, dst, cursor, esrc, E);

    long n4 = (long)N * 128 / 4;
    cvt_x_k<<<(int)((n4 + 255) / 256), 256, 0, stream>>>(X, Xb, n4);
    pack_w1_k<<<(3 * 16384 + 255) / 256, 256, 0, stream>>>(W1, Wp1);
    pack_w2_k<<<(16384 + 255) / 256, 256, 0, stream>>>(W2, Wp2);

    int nStripes = (N + 63) / 64;
    int gemm_grid = 512;
    int spmm_grid = (N + 3) / 4;

    gemm_mfma_k<1><<<gemm_grid, 256, 0, stream>>>(
        Xb, Wp1 + 2 * 16384, bufA, nullptr, nullptr, nullptr, norm, N, nStripes);
    spmm128_k<<<spmm_grid, 256, 0, stream>>>(bufA, bufB, rowptr, esrc, N);
    gemm_mfma_k<2><<<gemm_grid, 256, 0, stream>>>(
        Xb, Wp1 + 1 * 16384, bufB, nullptr, bufB, nullptr, norm, N, nStripes);
    spmm128_k<<<spmm_grid, 256, 0, stream>>>(bufB, bufA, rowptr, esrc, N);
    gemm_mfma_k<3><<<gemm_grid, 256, 0, stream>>>(
        Xb, Wp1, nullptr, h1b, bufA, b1, norm, N, nStripes);

    float* Z = bufA;
    float* u = bufB;
    gemm_mfma_k<0><<<gemm_grid, 256, 0, stream>>>(
        h1b, Wp2, Z, nullptr, nullptr, nullptr, norm, N, nStripes);
    spmm40_k<<<spmm_grid, 256, 0, stream>>>(Z, u, norm, rowptr, esrc, N);
    spmm40_final_k<<<2048, 256, 0, stream>>>(u, Z, b2, partial, norm, rowptr, esrc, N, 8192);
    reduce_mean_k<<<40, 256, 0, stream>>>(partial, out, 2048, 1.f / (float)N);
}

// Round 5
// 609.598 us; speedup vs baseline: 4.7032x; 1.2028x over previous
//
#include <hip/hip_runtime.h>

typedef unsigned short u16;
typedef __attribute__((ext_vector_type(8))) short bf16x8;
typedef __attribute__((ext_vector_type(4))) float f32x4;

__device__ inline u16 f2bf(float f) {
    union { float f; unsigned u; } v; v.f = f;
    unsigned r = v.u + 0x7fff + ((v.u >> 16) & 1);
    return (u16)(r >> 16);
}

__device__ inline float bflo(unsigned u) {
    union { unsigned u; float f; } v; v.u = u << 16; return v.f;
}
__device__ inline float bfhi(unsigned u) {
    union { unsigned u; float f; } v; v.u = u & 0xffff0000u; return v.f;
}

// ---------------------------------------------------------------------------
// graph preprocessing
// ---------------------------------------------------------------------------
__global__ void zero_int_k(int* __restrict__ p, int n) {
    int i = blockIdx.x * 256 + threadIdx.x;
    if (i < n) p[i] = 0;
}

__global__ void edge_deg_k(const int* __restrict__ dst, int* __restrict__ deg, int E) {
    int e = blockIdx.x * 256 + threadIdx.x;
    if (e < E) atomicAdd(&deg[dst[e]], 1);
}

__global__ void norm_k(const int* __restrict__ deg, float* __restrict__ norm, int n) {
    int i = blockIdx.x * 256 + threadIdx.x;
    if (i < n) {
        int d = deg[i];
        norm[i] = (d > 0) ? rsqrtf((float)d) : 0.f;
    }
}

__global__ void scan1_k(const int* __restrict__ deg, int* __restrict__ rowptr,
                        int* __restrict__ bsum, int n) {
    __shared__ int lds[256];
    int t = threadIdx.x;
    int base = blockIdx.x * 1024 + t * 4;
    int v[4];
    int s = 0;
#pragma unroll
    for (int i = 0; i < 4; ++i) {
        v[i] = s;
        int idx = base + i;
        s += (idx < n) ? deg[idx] : 0;
    }
    int x = s;
    lds[t] = x;
    __syncthreads();
    for (int off = 1; off < 256; off <<= 1) {
        int y = (t >= off) ? lds[t - off] : 0;
        __syncthreads();
        x += y;
        lds[t] = x;
        __syncthreads();
    }
    int toff = x - s;
    if (t == 255) bsum[blockIdx.x] = x;
#pragma unroll
    for (int i = 0; i < 4; ++i) {
        int idx = base + i;
        if (idx < n) rowptr[idx] = toff + v[i];
    }
}

__global__ void scan2_k(int* __restrict__ bsum, int nb) {
    if (blockIdx.x == 0 && threadIdx.x == 0) {
        int run = 0;
        for (int i = 0; i < nb; ++i) { int t = bsum[i]; bsum[i] = run; run += t; }
    }
}

__global__ void scan3_k(int* __restrict__ rowptr, int* __restrict__ cursor,
                        const int* __restrict__ bsum, int n, int E) {
    int t = threadIdx.x;
    int base = blockIdx.x * 1024 + t * 4;
    int boff = bsum[blockIdx.x];
#pragma unroll
    for (int i = 0; i < 4; ++i) {
        int idx = base + i;
        if (idx < n) {
            int v = rowptr[idx] + boff;
            rowptr[idx] = v;
            cursor[idx] = v;
        }
    }
    if (blockIdx.x == 0 && t == 0) rowptr[n] = E;
}

__global__ void scatter_k(const int* __restrict__ src, const int* __restrict__ dst,
                          int* __restrict__ cursor, int* __restrict__ esrc, int E) {
    int e = blockIdx.x * 256 + threadIdx.x;
    if (e < E) {
        int p = atomicAdd(&cursor[dst[e]], 1);
        esrc[p] = src[e];
    }
}

// ---------------------------------------------------------------------------
// prep: X -> bf16; W -> MFMA-fragment-packed bf16.
// Wp[((t*4+kk)*64+lane)*8+jj] = B[k][c], k = kk*32+(lane>>4)*8+jj, c = t*16+(lane&15)
// ---------------------------------------------------------------------------
__global__ void cvt_x_k(const float* __restrict__ X, u16* __restrict__ Xb, long n4) {
    long i = (long)blockIdx.x * 256 + threadIdx.x;
    if (i >= n4) return;
    float4 v = ((const float4*)X)[i];
    ushort4 o;
    o.x = f2bf(v.x); o.y = f2bf(v.y); o.z = f2bf(v.z); o.w = f2bf(v.w);
    ((ushort4*)Xb)[i] = o;
}

__global__ void pack_w1_k(const float* __restrict__ W1, u16* __restrict__ Wp) {
    int i = blockIdx.x * 256 + threadIdx.x;
    if (i >= 3 * 16384) return;
    int m = i >> 14, r = i & 16383;
    int jj = r & 7, lane = (r >> 3) & 63, kk = (r >> 9) & 3, t = r >> 11;
    int k = kk * 32 + (lane >> 4) * 8 + jj;
    int c = t * 16 + (lane & 15);
    Wp[i] = f2bf(W1[(size_t)m * 16384 + k * 128 + c]);
}

__global__ void pack_w2_k(const float* __restrict__ W2, u16* __restrict__ Wp) {
    int i = blockIdx.x * 256 + threadIdx.x;
    if (i >= 16384) return;
    int jj = i & 7, lane = (i >> 3) & 63, kk = (i >> 9) & 3, t = i >> 11;
    int k = kk * 32 + (lane >> 4) * 8 + jj;
    int c = t * 16 + (lane & 15);
    float v = 0.f;
    if (c < 120) {
        int hop = c / 40, j = c - hop * 40;
        v = W2[(size_t)(hop * 128 + k) * 40 + j];
    }
    Wp[i] = f2bf(v);
}

// ---------------------------------------------------------------------------
// MFMA GEMM: dot = A[n,128]b @ Wp.
// MODE 1: Cb = bf16(norm*dot)
// MODE 2: Cb = bf16(norm*(dot + norm*addp))      addp f32
// MODE 3: Cb = bf16(relu(dot + norm*addp + bias))
// MODE 0: Cf[n][120], cols>=80 scaled by norm (layer-2 combined, f32 out)
// ---------------------------------------------------------------------------
template <int MODE>
__global__ __launch_bounds__(256, 2) void gemm_mfma_k(
    const u16* __restrict__ Ab, const u16* __restrict__ Wp,
    float* __restrict__ Cf, u16* __restrict__ Cb,
    const float* __restrict__ addp, const float* __restrict__ bias,
    const float* __restrict__ norm, int n, int nStripes) {
    int lane = threadIdx.x & 63;
    int wave = threadIdx.x >> 6;
    int rit = lane & 15;
    int kgrp = lane >> 4;

    bf16x8 bfr[8][4];
    const bf16x8* wp = (const bf16x8*)Wp;
#pragma unroll
    for (int t = 0; t < 8; ++t)
#pragma unroll
        for (int kk = 0; kk < 4; ++kk)
            bfr[t][kk] = wp[(t * 4 + kk) * 64 + lane];

    for (int s = blockIdx.x; s < nStripes; s += gridDim.x) {
        int r0 = s * 64 + wave * 16;
        int ar = min(r0 + rit, n - 1);
        const bf16x8* arow = (const bf16x8*)(Ab + (size_t)ar * 128);
        bf16x8 afr[4];
#pragma unroll
        for (int kk = 0; kk < 4; ++kk) afr[kk] = arow[kk * 4 + kgrp];

        f32x4 acc[8];
#pragma unroll
        for (int t = 0; t < 8; ++t) acc[t] = (f32x4)(0.f);
#pragma unroll
        for (int kk = 0; kk < 4; ++kk)
#pragma unroll
            for (int t = 0; t < 8; ++t)
                acc[t] = __builtin_amdgcn_mfma_f32_16x16x32_bf16(
                    afr[kk], bfr[t][kk], acc[t], 0, 0, 0);

#pragma unroll
        for (int j = 0; j < 4; ++j) {
            int rs = r0 + kgrp * 4 + j;
            if (rs >= n) continue;
            float nr = norm[rs];
#pragma unroll
            for (int t = 0; t < 8; ++t) {
                int c = t * 16 + rit;
                float v = acc[t][j];
                if (MODE == 0) {
                    if (c < 120) {
                        if (c >= 80) v *= nr;
                        Cf[(size_t)rs * 120 + c] = v;
                    }
                } else if (MODE == 1) {
                    Cb[(size_t)rs * 128 + c] = f2bf(v * nr);
                } else if (MODE == 2) {
                    float ap = addp[(size_t)rs * 128 + c];
                    Cb[(size_t)rs * 128 + c] = f2bf(nr * (v + nr * ap));
                } else {
                    float ap = addp[(size_t)rs * 128 + c];
                    float r = fmaxf(v + nr * ap + bias[c], 0.f);
                    Cb[(size_t)rs * 128 + c] = f2bf(r);
                }
            }
        }
    }
}

// out[n,:] = sum_{e in in(n)} in[src(e),:]; in bf16[N][128], out f32[N][128].
// Quarter-wave (16 lanes x uint4 = 256 B) per edge, 4 edges/wave, 2x unroll.
__global__ __launch_bounds__(256) void spmm128_bf_k(
    const u16* __restrict__ in, float* __restrict__ out,
    const int* __restrict__ rowptr, const int* __restrict__ esrc, int n) {
    int gw = (blockIdx.x * 256 + threadIdx.x) >> 6;
    if (gw >= n) return;
    int lane = threadIdx.x & 63;
    int sub = lane >> 4;     // edge slot 0..3
    int l16 = lane & 15;     // column block (8 cols)
    int beg = rowptr[gw], end = rowptr[gw + 1];
    float a[8];
#pragma unroll
    for (int j = 0; j < 8; ++j) a[j] = 0.f;

    int e = beg + sub;
    for (; e + 4 < end; e += 8) {
        int s0 = esrc[e], s1 = esrc[e + 4];
        uint4 v0 = *(const uint4*)(in + (size_t)s0 * 128 + l16 * 8);
        uint4 v1 = *(const uint4*)(in + (size_t)s1 * 128 + l16 * 8);
        a[0] += bflo(v0.x); a[1] += bfhi(v0.x);
        a[2] += bflo(v0.y); a[3] += bfhi(v0.y);
        a[4] += bflo(v0.z); a[5] += bfhi(v0.z);
        a[6] += bflo(v0.w); a[7] += bfhi(v0.w);
        a[0] += bflo(v1.x); a[1] += bfhi(v1.x);
        a[2] += bflo(v1.y); a[3] += bfhi(v1.y);
        a[4] += bflo(v1.z); a[5] += bfhi(v1.z);
        a[6] += bflo(v1.w); a[7] += bfhi(v1.w);
    }
    for (; e < end; e += 4) {
        int s = esrc[e];
        uint4 v = *(const uint4*)(in + (size_t)s * 128 + l16 * 8);
        a[0] += bflo(v.x); a[1] += bfhi(v.x);
        a[2] += bflo(v.y); a[3] += bfhi(v.y);
        a[4] += bflo(v.z); a[5] += bfhi(v.z);
        a[6] += bflo(v.w); a[7] += bfhi(v.w);
    }
#pragma unroll
    for (int j = 0; j < 8; ++j) {
        a[j] += __shfl_xor(a[j], 16);
        a[j] += __shfl_xor(a[j], 32);
    }
    if (sub == 0) {
        float4 o0; o0.x = a[0]; o0.y = a[1]; o0.z = a[2]; o0.w = a[3];
        float4 o1; o1.x = a[4]; o1.y = a[5]; o1.z = a[6]; o1.w = a[7];
        *(float4*)(out + (size_t)gw * 128 + l16 * 8) = o0;
        *(float4*)(out + (size_t)gw * 128 + l16 * 8 + 4) = o1;
    }
}

// u'[n,j] = norm[n]*(Z[n,40+j] + norm[n]*sum_e Z[src(e),80+j]),  j<40
__global__ __launch_bounds__(256) void spmm40_k(
    const float* __restrict__ Z, float* __restrict__ u,
    const float* __restrict__ norm, const int* __restrict__ rowptr,
    const int* __restrict__ esrc, int n) {
    int gw = (blockIdx.x * 256 + threadIdx.x) >> 6;
    int lane = threadIdx.x & 63;
    if (gw >= n || lane >= 40) return;
    int beg = rowptr[gw], end = rowptr[gw + 1];
    float a = 0.f;
    int e = beg;
    for (; e + 3 < end; e += 4) {
        int s0 = esrc[e], s1 = esrc[e + 1], s2 = esrc[e + 2], s3 = esrc[e + 3];
        float v0 = Z[(size_t)s0 * 120 + 80 + lane];
        float v1 = Z[(size_t)s1 * 120 + 80 + lane];
        float v2 = Z[(size_t)s2 * 120 + 80 + lane];
        float v3 = Z[(size_t)s3 * 120 + 80 + lane];
        a += (v0 + v1) + (v2 + v3);
    }
    for (; e < end; ++e) a += Z[(size_t)esrc[e] * 120 + 80 + lane];
    float nn = norm[gw];
    u[(size_t)gw * 40 + lane] = nn * (Z[(size_t)gw * 120 + 40 + lane] + nn * a);
}

// r = relu(Z[n,0:40] + norm[n]*sum_e u'[src(e),:] + b2); partial-sum for mean
__global__ __launch_bounds__(256) void spmm40_final_k(
    const float* __restrict__ u, const float* __restrict__ Z, const float* __restrict__ bias,
    float* __restrict__ partial, const float* __restrict__ norm,
    const int* __restrict__ rowptr, const int* __restrict__ esrc, int n, int nwaves) {
    __shared__ float lds[4][40];
    int wave = threadIdx.x >> 6;
    int lane = threadIdx.x & 63;
    int gw0 = blockIdx.x * 4 + wave;
    float accm = 0.f;
    float bb = (lane < 40) ? bias[lane] : 0.f;
    for (int node = gw0; node < n; node += nwaves) {
        if (lane < 40) {
            int beg = rowptr[node], end = rowptr[node + 1];
            float a = 0.f;
            int e = beg;
            for (; e + 3 < end; e += 4) {
                int s0 = esrc[e], s1 = esrc[e + 1], s2 = esrc[e + 2], s3 = esrc[e + 3];
                float v0 = u[(size_t)s0 * 40 + lane];
                float v1 = u[(size_t)s1 * 40 + lane];
                float v2 = u[(size_t)s2 * 40 + lane];
                float v3 = u[(size_t)s3 * 40 + lane];
                a += (v0 + v1) + (v2 + v3);
            }
            for (; e < end; ++e) a += u[(size_t)esrc[e] * 40 + lane];
            float r = Z[(size_t)node * 120 + lane] + norm[node] * a + bb;
            accm += fmaxf(r, 0.f);
        }
    }
    if (lane < 40) lds[wave][lane] = accm;
    __syncthreads();
    if (threadIdx.x < 40) {
        partial[blockIdx.x * 40 + threadIdx.x] =
            lds[0][threadIdx.x] + lds[1][threadIdx.x] + lds[2][threadIdx.x] + lds[3][threadIdx.x];
    }
}

__global__ __launch_bounds__(256) void reduce_mean_k(
    const float* __restrict__ partial, float* __restrict__ out, int nb, float invN) {
    __shared__ float lds[256];
    int c = blockIdx.x, t = threadIdx.x;
    float s = 0.f;
    for (int i = t; i < nb; i += 256) s += partial[(size_t)i * 40 + c];
    lds[t] = s;
    __syncthreads();
    for (int o = 128; o > 0; o >>= 1) {
        if (t < o) lds[t] += lds[t + o];
        __syncthreads();
    }
    if (t == 0) out[c] = lds[0] * invN;
}

extern "C" void kernel_launch(void* const* d_in, const int* in_sizes, int n_in,
                              void* d_out, int out_size, void* d_ws, size_t ws_size,
                              hipStream_t stream) {
    const float* X   = (const float*)d_in[0];
    const int*   src = (const int*)d_in[1];
    const int*   dst = (const int*)d_in[2];
    const float* W1  = (const float*)d_in[3];
    const float* b1  = (const float*)d_in[4];
    const float* W2  = (const float*)d_in[5];
    const float* b2  = (const float*)d_in[6];
    float* out = (float*)d_out;

    const int IN = 128;
    const int N = in_sizes[0] / IN;
    const int E = in_sizes[1];

    char* w = (char*)d_ws;
    size_t off = 0;
    auto alloc = [&](size_t bytes) -> char* {
        char* p = w + off;
        off = (off + bytes + 15) & ~(size_t)15;
        return p;
    };
    float* norm    = (float*)alloc((size_t)N * 4);
    int*   deg     = (int*)alloc((size_t)N * 4);
    int*   rowptr  = (int*)alloc((size_t)(N + 1) * 4);
    int*   cursor  = (int*)alloc((size_t)N * 4);
    int*   bsum    = (int*)alloc(1024 * 4);
    int*   esrc    = (int*)alloc((size_t)E * 4);
    u16*   Xb      = (u16*)alloc((size_t)N * 128 * 2);
    u16*   h1b     = (u16*)alloc((size_t)N * 128 * 2);
    u16*   g       = (u16*)alloc((size_t)N * 128 * 2);   // bf16 gather table (reused)
    u16*   Wp1     = (u16*)alloc(3 * 16384 * 2);
    u16*   Wp2     = (u16*)alloc(16384 * 2);
    float* bufF    = (float*)alloc((size_t)N * 128 * 4); // T (f32), later Z[N][120]
    float* ubuf    = (float*)alloc((size_t)N * 40 * 4);
    float* partial = (float*)alloc(2048 * 40 * 4);

    int nb_scan = (N + 1023) / 1024;

    zero_int_k<<<(N + 255) / 256, 256, 0, stream>>>(deg, N);
    edge_deg_k<<<(E + 255) / 256, 256, 0, stream>>>(dst, deg, E);
    norm_k<<<(N + 255) / 256, 256, 0, stream>>>(deg, norm, N);
    scan1_k<<<nb_scan, 256, 0, stream>>>(deg, rowptr, bsum, N);
    scan2_k<<<1, 64, 0, stream>>>(bsum, nb_scan);
    scan3_k<<<nb_scan, 256, 0, stream>>>(rowptr, cursor, bsum, N, E);
    scatter_k<<<(E + 255) / 256, 256, 0, stream>>>(src, dst, cursor, esrc, E);

    long n4 = (long)N * 128 / 4;
    cvt_x_k<<<(int)((n4 + 255) / 256), 256, 0, stream>>>(X, Xb, n4);
    pack_w1_k<<<(3 * 16384 + 255) / 256, 256, 0, stream>>>(W1, Wp1);
    pack_w2_k<<<(16384 + 255) / 256, 256, 0, stream>>>(W2, Wp2);

    int nStripes = (N + 63) / 64;
    int gemm_grid = 512;
    int spmm_grid = (N + 3) / 4;

    // layer 1: h1 = relu(X@W0 + A(X@W1 + A(X@W2)) + b1)
    gemm_mfma_k<1><<<gemm_grid, 256, 0, stream>>>(
        Xb, Wp1 + 2 * 16384, nullptr, g, nullptr, nullptr, norm, N, nStripes);
    spmm128_bf_k<<<spmm_grid, 256, 0, stream>>>(g, bufF, rowptr, esrc, N);
    gemm_mfma_k<2><<<gemm_grid, 256, 0, stream>>>(
        Xb, Wp1 + 1 * 16384, nullptr, g, bufF, nullptr, norm, N, nStripes);
    spmm128_bf_k<<<spmm_grid, 256, 0, stream>>>(g, bufF, rowptr, esrc, N);
    gemm_mfma_k<3><<<gemm_grid, 256, 0, stream>>>(
        Xb, Wp1, nullptr, h1b, bufF, b1, norm, N, nStripes);

    // layer 2: out = mean(relu(Z0 + A(Z1 + A(Z2)) + b2))
    float* Z = bufF;   // [N][120]
    gemm_mfma_k<0><<<gemm_grid, 256, 0, stream>>>(
        h1b, Wp2, Z, nullptr, nullptr, nullptr, norm, N, nStripes);
    spmm40_k<<<spmm_grid, 256, 0, stream>>>(Z, ubuf, norm, rowptr, esrc, N);
    spmm40_final_k<<<2048, 256, 0, stream>>>(ubuf, Z, b2, partial, norm, rowptr, esrc, N, 8192);
    reduce_mean_k<<<40, 256, 0, stream>>>(partial, out, 2048, 1.f / (float)N);
}